// Round 2
// baseline (499.473 us; speedup 1.0000x reference)
//
#include <hip/hip_runtime.h>
#include <hip/hip_bf16.h>
#include <stdint.h>

#define BSZ 32
#define TT 128
#define NAG 16
#define NROW 4096
#define NAR 65536
#define EPSV 1e-6f

typedef __attribute__((ext_vector_type(2))) _Float16 half2v;

__device__ __forceinline__ float dot2f(uint32_t a, uint32_t b, float c) {
#if __has_builtin(__builtin_amdgcn_fdot2)
    return __builtin_amdgcn_fdot2(__builtin_bit_cast(half2v, a),
                                  __builtin_bit_cast(half2v, b), c, false);
#else
    half2v ha = __builtin_bit_cast(half2v, a);
    half2v hb = __builtin_bit_cast(half2v, b);
    return c + (float)ha.x*(float)hb.x + (float)ha.y*(float)hb.y;
#endif
}

__device__ __forceinline__ uint32_t packh2(float a, float b) {
    union { half2v h; uint32_t u; } cu;
    cu.h.x = (_Float16)a; cu.h.y = (_Float16)b;
    return cu.u;
}

__device__ __forceinline__ float sigm(float x) { return 1.f/(1.f + __expf(-x)); }
__device__ __forceinline__ float tanh_f(float x) { return 1.f - 2.f/(__expf(2.f*x) + 1.f); }

// ---------------- K0: pack Wh into per-thread f16 layout for the scan ----------------
// scan thread t (512): q=t>>7 (k-quarter), c0=t&127; owns cols c0+128*i (i<6), k in [64q,64q+64)
// slot d = i*32+dd  ->  pair (k=64q+2dd, k+1) of column c0+128i
__global__ void k_prep_wh(const float* __restrict__ Wh, uint32_t* __restrict__ WhP) {
    int g = blockIdx.x*256 + threadIdx.x;
    if (g >= 512*192) return;
    int t = g & 511, d = g >> 9;
    int q = t >> 7, c0 = t & 127;
    int i = d >> 5, dd = d & 31;
    int c = c0 + 128*i;
    int k = 64*q + 2*dd;
    WhP[d*512 + t] = packh2(Wh[k*768 + c], Wh[(k+1)*768 + c]);
}

// ---------------- f32 tiled GEMM: C[M,N] = A[M,K]@B[K,N] + bias ----------------
// AMODE 0: A direct with lda. AMODE 1: A gathered from obs (row r, col k -> obs[r*2048+(k>>6)*128+(k&63)])
template<int AMODE>
__global__ __launch_bounds__(256)
void k_gemm(const float* __restrict__ Ap, const float* __restrict__ Bp,
            const float* __restrict__ bias, float* __restrict__ Cp,
            int N, int K, int lda)
{
    __shared__ float As[16][132];
    __shared__ float Bs[16][132];
    int tid = threadIdx.x;
    int ty = tid >> 4, tx = tid & 15;
    int m0 = blockIdx.x * 128, n0 = blockIdx.y * 128;
    float acc[8][8] = {};
    for (int k0 = 0; k0 < K; k0 += 16) {
#pragma unroll
        for (int rep = 0; rep < 2; ++rep) {
            int idx = rep*256 + tid;
            int row = idx >> 2, seg = idx & 3;
            int kk = k0 + seg*4;
            const float* ga;
            if (AMODE == 1) ga = Ap + (size_t)(m0+row)*2048 + (kk>>6)*128 + (kk&63);
            else            ga = Ap + (size_t)(m0+row)*lda + kk;
            float4 v = *(const float4*)ga;
            As[seg*4+0][row] = v.x; As[seg*4+1][row] = v.y;
            As[seg*4+2][row] = v.z; As[seg*4+3][row] = v.w;
        }
#pragma unroll
        for (int rep = 0; rep < 2; ++rep) {
            int idx = rep*256 + tid;
            int kr = idx >> 5, seg = idx & 31;
            float4 v = *(const float4*)(Bp + (size_t)(k0+kr)*N + n0 + seg*4);
            *(float4*)&Bs[kr][seg*4] = v;
        }
        __syncthreads();
#pragma unroll
        for (int kk = 0; kk < 16; ++kk) {
            float a8[8], b8[8];
            *(float4*)&a8[0] = *(const float4*)&As[kk][ty*8];
            *(float4*)&a8[4] = *(const float4*)&As[kk][ty*8+4];
            *(float4*)&b8[0] = *(const float4*)&Bs[kk][tx*8];
            *(float4*)&b8[4] = *(const float4*)&Bs[kk][tx*8+4];
#pragma unroll
            for (int i = 0; i < 8; ++i)
#pragma unroll
                for (int j = 0; j < 8; ++j)
                    acc[i][j] = fmaf(a8[i], b8[j], acc[i][j]);
        }
        __syncthreads();
    }
#pragma unroll
    for (int i = 0; i < 8; ++i) {
        int row = m0 + ty*8 + i;
#pragma unroll
        for (int j = 0; j < 8; ++j) {
            int col = n0 + tx*8 + j;
            Cp[(size_t)row*N + col] = acc[i][j] + bias[col];
        }
    }
}

// ---------------- K2: GRU scan, one WG per batch chain, Wh f16 register-resident ----------------
__global__ __launch_bounds__(512, 2)
void k_scan(const uint32_t* __restrict__ WhP, const float* __restrict__ XG,
            float* __restrict__ h_all)
{
    __shared__ float h32[256];
    __shared__ uint32_t h16[128];     // h packed as f16 pairs (k, k+1)
    __shared__ float psum[4][768];
    int t = threadIdx.x;
    int b = blockIdx.x;
    int q = t >> 7, c0 = t & 127;
    uint32_t w[192];
#pragma unroll
    for (int d = 0; d < 192; ++d) w[d] = WhP[d*512 + t];
    if (t < 256) h32[t] = 0.f;
    if (t < 128) h16[t] = 0u;
    __syncthreads();
    const float* xgb = XG + (size_t)b*TT*768;
    for (int st = 0; st < TT; ++st) {
        float xgr = 0.f, xgz = 0.f, xgn = 0.f;
        if (t < 256) {
            const float* xgp = xgb + st*768;
            xgr = xgp[t]; xgz = xgp[256+t]; xgn = xgp[512+t];
        }
        float acc[6] = {0.f,0.f,0.f,0.f,0.f,0.f};
        const uint4* hq4 = (const uint4*)&h16[q*32];
#pragma unroll
        for (int b8 = 0; b8 < 8; ++b8) {
            uint4 hv = hq4[b8];
#pragma unroll
            for (int i = 0; i < 6; ++i) {
                acc[i] = dot2f(hv.x, w[i*32 + b8*4 + 0], acc[i]);
                acc[i] = dot2f(hv.y, w[i*32 + b8*4 + 1], acc[i]);
                acc[i] = dot2f(hv.z, w[i*32 + b8*4 + 2], acc[i]);
                acc[i] = dot2f(hv.w, w[i*32 + b8*4 + 3], acc[i]);
            }
        }
#pragma unroll
        for (int i = 0; i < 6; ++i) psum[q][c0 + 128*i] = acc[i];
        __syncthreads();
        if (t < 256) {
            float hr = psum[0][t]     + psum[1][t]     + psum[2][t]     + psum[3][t];
            float hz = psum[0][256+t] + psum[1][256+t] + psum[2][256+t] + psum[3][256+t];
            float hn = psum[0][512+t] + psum[1][512+t] + psum[2][512+t] + psum[3][512+t];
            float rg = sigm(xgr + hr);
            float zg = sigm(xgz + hz);
            float ng = tanh_f(xgn + rg*hn);
            float hnew = (1.f - zg)*ng + zg*h32[t];
            h32[t] = hnew;
            union { _Float16 h; uint16_t u; } cu; cu.h = (_Float16)hnew;
            ((uint16_t*)h16)[t] = cu.u;
            h_all[((size_t)b*TT + st)*256 + t] = hnew;
        }
        __syncthreads();
    }
}

// ---------------- K4: hypergraph conv per (b,t); writes graphs + packed-f16 emb ----------------
__global__ __launch_bounds__(256)
void k_hyper(const float* __restrict__ h_all, const float* __restrict__ obs,
             const float* __restrict__ W_inc, const float* __restrict__ b_inc,
             const float* __restrict__ W_hg,
             float* __restrict__ graphs, uint32_t* __restrict__ emb_pk)
{
    __shared__ float hs[256];
    __shared__ float hm[128];
    __shared__ float rdv[16];
    __shared__ float rde[8];
    __shared__ float xs[16][64];
    __shared__ float msg[8][64];
    __shared__ float outs[16][64];
    int r = blockIdx.x;
    int t = threadIdx.x;
    hs[t] = h_all[(size_t)r*256 + t];
    __syncthreads();
    if (t < 128) {
        float a = b_inc[t];
#pragma unroll 8
        for (int k = 0; k < 256; ++k) a = fmaf(hs[k], W_inc[k*128 + t], a);
        float s = sigm(a);
        hm[t] = s;
        graphs[(size_t)r*128 + t] = s;
    }
    __syncthreads();
    if (t < 16) {
        float s = EPSV;
#pragma unroll
        for (int e = 0; e < 8; ++e) s += hm[t*8 + e];
        rdv[t] = 1.f/sqrtf(s);
    } else if (t >= 64 && t < 72) {
        int e = t - 64;
        float s = EPSV;
#pragma unroll
        for (int a2 = 0; a2 < 16; ++a2) s += hm[a2*8 + e];
        rde[e] = 1.f/s;
    }
    __syncthreads();
    {
        int aa = t >> 4, f4 = t & 15;
        float4 v = *(const float4*)(obs + (size_t)r*2048 + aa*128 + f4*4);
        float sc = rdv[aa];
        *(float4*)&xs[aa][f4*4] = make_float4(v.x*sc, v.y*sc, v.z*sc, v.w*sc);
    }
    __syncthreads();
#pragma unroll
    for (int rep = 0; rep < 2; ++rep) {
        int o = rep*256 + t;
        int e = o >> 6, f = o & 63;
        float s = 0.f;
#pragma unroll
        for (int a2 = 0; a2 < 16; ++a2) s = fmaf(hm[a2*8 + e], xs[a2][f], s);
        msg[e][f] = s * rde[e];
    }
    __syncthreads();
#pragma unroll
    for (int rep = 0; rep < 4; ++rep) {
        int o = rep*256 + t;
        int a2 = o >> 6, f = o & 63;
        float s = 0.f;
#pragma unroll
        for (int e = 0; e < 8; ++e) s = fmaf(hm[a2*8 + e], msg[e][f], s);
        outs[a2][f] = s * rdv[a2];
    }
    __syncthreads();
    {
        int aa = t >> 4, fo0 = (t & 15)*4;
        float s0=0,s1=0,s2=0,s3=0;
#pragma unroll 8
        for (int f = 0; f < 64; ++f) {
            float ov = outs[aa][f];
            float4 wv = *(const float4*)(W_hg + f*64 + fo0);
            s0 = fmaf(ov, wv.x, s0); s1 = fmaf(ov, wv.y, s1);
            s2 = fmaf(ov, wv.z, s2); s3 = fmaf(ov, wv.w, s3);
        }
        s0 = fmaxf(s0,0.f); s1 = fmaxf(s1,0.f); s2 = fmaxf(s2,0.f); s3 = fmaxf(s3,0.f);
        uint2 pk; pk.x = packh2(s0, s1); pk.y = packh2(s2, s3);
        *(uint2*)&emb_pk[((size_t)r*16 + aa)*32 + (t & 15)*2] = pk;
    }
}

// ---------------- K5: fused MLP head per 64 rows; x1 stays in LDS (f16), q reduced in-wave ----------------
__global__ __launch_bounds__(256)
void k_mlp(const uint32_t* __restrict__ emb_pk, const float* __restrict__ S1,
           const float* __restrict__ W1, const float* __restrict__ W2,
           const float* __restrict__ b2, const float* __restrict__ W3,
           const float* __restrict__ b3, float* __restrict__ qout)
{
    __shared__ uint32_t x1s[64][132];     // x1 packed f16 pairs along k
    __shared__ uint32_t stageU[16][260];  // staged packed weights (16 k-pairs x 256 cols)
    __shared__ uint32_t embs[64][34];     // emb packed f16 pairs
    int tid = threadIdx.x;
    int ty = tid >> 5, tx = tid & 31;
    int rowbase = blockIdx.x * 64;
#pragma unroll
    for (int rep = 0; rep < 8; ++rep) {
        int idx = rep*256 + tid;
        int row = idx >> 5, dp = idx & 31;
        embs[row][dp] = emb_pk[(size_t)(rowbase + row)*32 + dp];
    }
    float acc[8][8];
#pragma unroll
    for (int i = 0; i < 8; ++i) {
        int row = rowbase + ty*8 + i;
        int rr = row >> 4, aa = row & 15;
        const float* s1p = S1 + (size_t)rr*256;
        const float* wap = W1 + (size_t)(256 + aa)*256;
#pragma unroll
        for (int j = 0; j < 8; ++j) {
            int col = tx*8 + j;
            acc[i][j] = s1p[col] + wap[col];   // b1 already folded into S1
        }
    }
    __syncthreads();
    // phase A: emb @ W1[272:336]  (K=64 -> 32 k-pairs in 2 chunks)
    for (int ch = 0; ch < 2; ++ch) {
#pragma unroll
        for (int rep = 0; rep < 16; ++rep) {
            int idx = rep*256 + tid;
            int kpr = idx >> 8, c = idx & 255;
            int krow = 272 + ch*32 + 2*kpr;
            stageU[kpr][c] = packh2(W1[(size_t)krow*256 + c], W1[(size_t)(krow+1)*256 + c]);
        }
        __syncthreads();
#pragma unroll
        for (int kp = 0; kp < 16; ++kp) {
            uint32_t a_[8];
#pragma unroll
            for (int i = 0; i < 8; ++i) a_[i] = embs[ty*8 + i][ch*16 + kp];
            uint4 b0 = *(const uint4*)&stageU[kp][tx*8];
            uint4 b1v = *(const uint4*)&stageU[kp][tx*8 + 4];
            uint32_t b_[8] = {b0.x,b0.y,b0.z,b0.w,b1v.x,b1v.y,b1v.z,b1v.w};
#pragma unroll
            for (int i = 0; i < 8; ++i)
#pragma unroll
                for (int j = 0; j < 8; ++j)
                    acc[i][j] = dot2f(a_[i], b_[j], acc[i][j]);
        }
        __syncthreads();
    }
#pragma unroll
    for (int i = 0; i < 8; ++i) {
        uint4 pk;
        pk.x = packh2(fmaxf(acc[i][0],0.f), fmaxf(acc[i][1],0.f));
        pk.y = packh2(fmaxf(acc[i][2],0.f), fmaxf(acc[i][3],0.f));
        pk.z = packh2(fmaxf(acc[i][4],0.f), fmaxf(acc[i][5],0.f));
        pk.w = packh2(fmaxf(acc[i][6],0.f), fmaxf(acc[i][7],0.f));
        *(uint4*)&x1s[ty*8 + i][tx*4] = pk;
    }
#pragma unroll
    for (int i = 0; i < 8; ++i)
#pragma unroll
        for (int j = 0; j < 8; ++j) acc[i][j] = 0.f;
    __syncthreads();
    // phase B: x1 @ W2  (K=256 -> 128 k-pairs in 8 chunks)
    for (int ch = 0; ch < 8; ++ch) {
#pragma unroll
        for (int rep = 0; rep < 16; ++rep) {
            int idx = rep*256 + tid;
            int kpr = idx >> 8, c = idx & 255;
            int krow = ch*32 + 2*kpr;
            stageU[kpr][c] = packh2(W2[(size_t)krow*256 + c], W2[(size_t)(krow+1)*256 + c]);
        }
        __syncthreads();
#pragma unroll
        for (int kp = 0; kp < 16; ++kp) {
            uint32_t a_[8];
#pragma unroll
            for (int i = 0; i < 8; ++i) a_[i] = x1s[ty*8 + i][ch*16 + kp];
            uint4 b0 = *(const uint4*)&stageU[kp][tx*8];
            uint4 b1v = *(const uint4*)&stageU[kp][tx*8 + 4];
            uint32_t b_[8] = {b0.x,b0.y,b0.z,b0.w,b1v.x,b1v.y,b1v.z,b1v.w};
#pragma unroll
            for (int i = 0; i < 8; ++i)
#pragma unroll
                for (int j = 0; j < 8; ++j)
                    acc[i][j] = dot2f(a_[i], b_[j], acc[i][j]);
        }
        __syncthreads();
    }
    float w3v[8], b2v[8];
#pragma unroll
    for (int j = 0; j < 8; ++j) { w3v[j] = W3[tx*8 + j]; b2v[j] = b2[tx*8 + j]; }
    float bb3 = b3[0];
#pragma unroll
    for (int i = 0; i < 8; ++i) {
        float qp = 0.f;
#pragma unroll
        for (int j = 0; j < 8; ++j) {
            float x2 = fmaxf(acc[i][j] + b2v[j], 0.f);
            qp = fmaf(x2, w3v[j], qp);
        }
        qp += __shfl_xor(qp, 1);
        qp += __shfl_xor(qp, 2);
        qp += __shfl_xor(qp, 4);
        qp += __shfl_xor(qp, 8);
        qp += __shfl_xor(qp, 16);
        if (tx == 0) qout[rowbase + ty*8 + i] = qp + bb3;
    }
}

extern "C" void kernel_launch(void* const* d_in, const int* in_sizes, int n_in,
                              void* d_out, int out_size, void* d_ws, size_t ws_size,
                              hipStream_t stream)
{
    const float* state = (const float*)d_in[0];
    const float* obs   = (const float*)d_in[1];
    const float* Wx    = (const float*)d_in[2];
    const float* Wh    = (const float*)d_in[3];
    const float* b_gru = (const float*)d_in[4];
    const float* W_inc = (const float*)d_in[5];
    const float* b_inc = (const float*)d_in[6];
    const float* W_hg  = (const float*)d_in[7];
    const float* W1    = (const float*)d_in[8];
    const float* b1    = (const float*)d_in[9];
    const float* W2    = (const float*)d_in[10];
    const float* b2    = (const float*)d_in[11];
    const float* W3    = (const float*)d_in[12];
    const float* b3    = (const float*)d_in[13];
    float* qout   = (float*)d_out;
    float* graphs = (float*)d_out + NAR;

    float* base = (float*)d_ws;
    float* XG   = base;                                  // 4096*768
    float* hall = base + 3145728;                        // 4096*256
    float* S1   = base + 4194304;                        // 4096*256
    uint32_t* emb_pk = (uint32_t*)(base + 5242880);      // 65536*32 dwords
    uint32_t* WhP    = (uint32_t*)(base + 7340032);      // 512*192 dwords

    hipLaunchKernelGGL(k_prep_wh, dim3(384), dim3(256), 0, stream, Wh, WhP);
    hipLaunchKernelGGL((k_gemm<1>), dim3(32, 6), dim3(256), 0, stream,
                       obs, Wx, b_gru, XG, 768, 1024, 0);
    hipLaunchKernelGGL((k_gemm<0>), dim3(32, 2), dim3(256), 0, stream,
                       state, W1, b1, S1, 256, 256, 256);
    hipLaunchKernelGGL(k_scan, dim3(32), dim3(512), 0, stream, WhP, XG, hall);
    hipLaunchKernelGGL(k_hyper, dim3(4096), dim3(256), 0, stream,
                       hall, obs, W_inc, b_inc, W_hg, graphs, emb_pk);
    hipLaunchKernelGGL(k_mlp, dim3(1024), dim3(256), 0, stream,
                       emb_pk, S1, W1, W2, b2, W3, b3, qout);
}

// Round 3
// 263.880 us; speedup vs baseline: 1.8928x; 1.8928x over previous
//
#include <hip/hip_runtime.h>
#include <hip/hip_bf16.h>
#include <stdint.h>

#define BSZ 32
#define TT 128
#define NAG 16
#define NROW 4096
#define NAR 65536
#define EPSV 1e-6f

typedef __attribute__((ext_vector_type(2))) _Float16 half2v;
typedef _Float16 f16x8 __attribute__((ext_vector_type(8)));
typedef float f32x4 __attribute__((ext_vector_type(4)));

#define MFMA16(a,b,c) __builtin_amdgcn_mfma_f32_16x16x32_f16(a,b,c,0,0,0)

__device__ __forceinline__ float dot2f(uint32_t a, uint32_t b, float c) {
#if __has_builtin(__builtin_amdgcn_fdot2)
    return __builtin_amdgcn_fdot2(__builtin_bit_cast(half2v, a),
                                  __builtin_bit_cast(half2v, b), c, false);
#else
    half2v ha = __builtin_bit_cast(half2v, a);
    half2v hb = __builtin_bit_cast(half2v, b);
    return c + (float)ha.x*(float)hb.x + (float)ha.y*(float)hb.y;
#endif
}

__device__ __forceinline__ uint32_t packh2(float a, float b) {
    union { half2v h; uint32_t u; } cu;
    cu.h.x = (_Float16)a; cu.h.y = (_Float16)b;
    return cu.u;
}

__device__ __forceinline__ float sigm(float x) { return 1.f/(1.f + __expf(-x)); }
__device__ __forceinline__ float tanh_f(float x) { return 1.f - 2.f/(__expf(2.f*x) + 1.f); }

// async 16B global->LDS; dest = wave-uniform base + lane*16 (linear)
__device__ __forceinline__ void gl_lds16(const uint32_t* g, uint32_t* lwb, int lane) {
#if __has_builtin(__builtin_amdgcn_global_load_lds)
    __builtin_amdgcn_global_load_lds(
        (const __attribute__((address_space(1))) uint32_t*)g,
        (__attribute__((address_space(3))) uint32_t*)lwb, 16, 0, 0);
#else
    *(uint4*)(lwb + lane*4) = *(const uint4*)g;
#endif
}

// ---------------- K0: pack Wh into per-thread f16 layout for the scan ----------------
__global__ void k_prep_wh(const float* __restrict__ Wh, uint32_t* __restrict__ WhP) {
    int g = blockIdx.x*256 + threadIdx.x;
    if (g >= 512*192) return;
    int t = g & 511, d = g >> 9;
    int q = t >> 7, c0 = t & 127;
    int i = d >> 5, dd = d & 31;
    int c = c0 + 128*i;
    int k = 64*q + 2*dd;
    WhP[d*512 + t] = packh2(Wh[k*768 + c], Wh[(k+1)*768 + c]);
}

// ---------------- cvt: obs -> f16 packed rows [4096][1024] (gather 64 feats/agent) ----
__global__ __launch_bounds__(256)
void k_cvt_obs(const float* __restrict__ obs, uint32_t* __restrict__ obs16) {
    int idx = blockIdx.x*256 + threadIdx.x;   // uint4 idx over 4096*128
    int r = idx >> 7, q = idx & 127;
    int a = q >> 3, f8 = (q & 7)*8;
    const float* p = obs + ((size_t)r*16 + a)*128 + f8;
    float4 v0 = *(const float4*)p, v1 = *(const float4*)(p+4);
    uint4 o; o.x=packh2(v0.x,v0.y); o.y=packh2(v0.z,v0.w);
    o.z=packh2(v1.x,v1.y); o.w=packh2(v1.z,v1.w);
    *(uint4*)(obs16 + (size_t)idx*4) = o;
}

// ---------------- cvt: state -> f16 [4096][256] ----------------
__global__ __launch_bounds__(256)
void k_cvt_state(const float* __restrict__ st, uint32_t* __restrict__ st16) {
    int idx = blockIdx.x*256 + threadIdx.x;   // uint4 idx over 4096*32
    int r = idx >> 5, q = idx & 31;
    const float* p = st + (size_t)r*256 + q*8;
    float4 v0 = *(const float4*)p, v1 = *(const float4*)(p+4);
    uint4 o; o.x=packh2(v0.x,v0.y); o.y=packh2(v0.z,v0.w);
    o.z=packh2(v1.x,v1.y); o.w=packh2(v1.z,v1.w);
    *(uint4*)(st16 + (size_t)idx*4) = o;
}

// ---------------- transpose+cvt: src f32 [K][N] -> out u32-packed [N][K/2] ----------
__global__ __launch_bounds__(256)
void k_tr(const float* __restrict__ src, uint32_t* __restrict__ out, int N, int Khalf) {
    __shared__ float t_[64][65];
    int k0 = blockIdx.x*64, n0 = blockIdx.y*64;
    int tid = threadIdx.x;
#pragma unroll
    for (int rep = 0; rep < 4; ++rep) {
        int idx = rep*256 + tid;
        int r = idx >> 4, c4 = (idx & 15)*4;
        float4 v = *(const float4*)(src + (size_t)(k0+r)*N + n0 + c4);
        t_[r][c4] = v.x; t_[r][c4+1] = v.y; t_[r][c4+2] = v.z; t_[r][c4+3] = v.w;
    }
    __syncthreads();
#pragma unroll
    for (int rep = 0; rep < 8; ++rep) {
        int idx = rep*256 + tid;
        int nl = idx >> 5, kp = idx & 31;
        out[(size_t)(n0+nl)*Khalf + (k0>>1) + kp] = packh2(t_[kp*2][nl], t_[kp*2+1][nl]);
    }
}

// ---------------- MFMA f16 GEMM: C[M,N] = A16[M,K] @ BT16[N,K]^T + bias ----------------
// 128x128 tile, BK=64, dbuf LDS, gload_lds w/ pre-swizzled source, 256 thr (2x2 waves of 64x64)
__global__ __launch_bounds__(256, 2)
void k_xg(const uint32_t* __restrict__ A16, const uint32_t* __restrict__ BT16,
          const float* __restrict__ bias, float* __restrict__ Cp,
          int N, int K, int nTilesN)
{
    __shared__ __align__(16) uint32_t lds[2][8192];   // per buf: A[128][64]f16 | B[128][64]f16
    int nwg = gridDim.x;
    int bid = blockIdx.x;
    int qq = nwg >> 3;                 // grids are multiples of 8
    int logical = (bid & 7)*qq + (bid >> 3);   // XCD-chunked swizzle
    int bm = logical / nTilesN, bn = logical % nTilesN;
    int m0 = bm*128, n0 = bn*128;
    int tid = threadIdx.x;
    int lane = tid & 63, wave = tid >> 6;
    int wr = wave >> 1, wc = wave & 1;
    int Ku = K >> 1;                   // u32 per row

    f32x4 acc[4][4];
#pragma unroll
    for (int i = 0; i < 4; ++i)
#pragma unroll
        for (int j = 0; j < 4; ++j) acc[i][j] = (f32x4){0.f,0.f,0.f,0.f};

    // stage K-step k0 into buf: 2048 16B-chunks (A first 1024, B next)
    auto STAGE = [&](int buf, int k0) {
#pragma unroll
        for (int i = 0; i < 8; ++i) {
            int c = i*256 + tid;
            int cr = c & 1023;
            int row = cr >> 3, kq = cr & 7;
            const uint32_t* src;
            if (c < 1024) src = A16 + (size_t)(m0+row)*Ku + (k0>>1) + ((kq ^ (row&7))<<2);
            else          src = BT16 + (size_t)(n0+row)*Ku + (k0>>1) + ((kq ^ (row&7))<<2);
            gl_lds16(src, &lds[buf][(size_t)((i*256 + (wave<<6))<<2)], lane);
        }
    };

    STAGE(0, 0);
    __syncthreads();
    int NT = K >> 6;
    for (int t = 0; t < NT; ++t) {
        int cur = t & 1;
        if (t + 1 < NT) STAGE(cur ^ 1, (t+1) << 6);
        const uint32_t* Ab = &lds[cur][0];
        const uint32_t* Bb = &lds[cur][4096];
#pragma unroll
        for (int kk = 0; kk < 2; ++kk) {
            f16x8 af[4], bf[4];
#pragma unroll
            for (int im = 0; im < 4; ++im) {
                int row = wr*64 + im*16 + (lane & 15);
                int ck = (kk*4 + (lane >> 4)) ^ (row & 7);
                af[im] = *(const f16x8*)(Ab + row*32 + ck*4);
            }
#pragma unroll
            for (int in = 0; in < 4; ++in) {
                int row = wc*64 + in*16 + (lane & 15);
                int ck = (kk*4 + (lane >> 4)) ^ (row & 7);
                bf[in] = *(const f16x8*)(Bb + row*32 + ck*4);
            }
#pragma unroll
            for (int im = 0; im < 4; ++im)
#pragma unroll
                for (int in = 0; in < 4; ++in)
                    acc[im][in] = MFMA16(af[im], bf[in], acc[im][in]);
        }
        __syncthreads();
    }
    // epilogue: D[row][col], row=(lane>>4)*4+r, col=lane&15 within each 16x16 frag
#pragma unroll
    for (int im = 0; im < 4; ++im)
#pragma unroll
        for (int in = 0; in < 4; ++in) {
            int col = n0 + wc*64 + in*16 + (lane & 15);
            float bv = bias[col];
#pragma unroll
            for (int r = 0; r < 4; ++r) {
                int row = m0 + wr*64 + im*16 + (lane >> 4)*4 + r;
                Cp[(size_t)row*N + col] = acc[im][in][r] + bv;
            }
        }
}

// ---------------- K2: GRU scan (unchanged) ----------------
__global__ __launch_bounds__(512, 2)
void k_scan(const uint32_t* __restrict__ WhP, const float* __restrict__ XG,
            float* __restrict__ h_all)
{
    __shared__ float h32[256];
    __shared__ uint32_t h16[128];
    __shared__ float psum[4][768];
    int t = threadIdx.x;
    int b = blockIdx.x;
    int q = t >> 7, c0 = t & 127;
    uint32_t w[192];
#pragma unroll
    for (int d = 0; d < 192; ++d) w[d] = WhP[d*512 + t];
    if (t < 256) h32[t] = 0.f;
    if (t < 128) h16[t] = 0u;
    __syncthreads();
    const float* xgb = XG + (size_t)b*TT*768;
    for (int st = 0; st < TT; ++st) {
        float xgr = 0.f, xgz = 0.f, xgn = 0.f;
        if (t < 256) {
            const float* xgp = xgb + st*768;
            xgr = xgp[t]; xgz = xgp[256+t]; xgn = xgp[512+t];
        }
        float acc[6] = {0.f,0.f,0.f,0.f,0.f,0.f};
        const uint4* hq4 = (const uint4*)&h16[q*32];
#pragma unroll
        for (int b8 = 0; b8 < 8; ++b8) {
            uint4 hv = hq4[b8];
#pragma unroll
            for (int i = 0; i < 6; ++i) {
                acc[i] = dot2f(hv.x, w[i*32 + b8*4 + 0], acc[i]);
                acc[i] = dot2f(hv.y, w[i*32 + b8*4 + 1], acc[i]);
                acc[i] = dot2f(hv.z, w[i*32 + b8*4 + 2], acc[i]);
                acc[i] = dot2f(hv.w, w[i*32 + b8*4 + 3], acc[i]);
            }
        }
#pragma unroll
        for (int i = 0; i < 6; ++i) psum[q][c0 + 128*i] = acc[i];
        __syncthreads();
        if (t < 256) {
            float hr = psum[0][t]     + psum[1][t]     + psum[2][t]     + psum[3][t];
            float hz = psum[0][256+t] + psum[1][256+t] + psum[2][256+t] + psum[3][256+t];
            float hn = psum[0][512+t] + psum[1][512+t] + psum[2][512+t] + psum[3][512+t];
            float rg = sigm(xgr + hr);
            float zg = sigm(xgz + hz);
            float ng = tanh_f(xgn + rg*hn);
            float hnew = (1.f - zg)*ng + zg*h32[t];
            h32[t] = hnew;
            union { _Float16 h; uint16_t u; } cu; cu.h = (_Float16)hnew;
            ((uint16_t*)h16)[t] = cu.u;
            h_all[((size_t)b*TT + st)*256 + t] = hnew;
        }
        __syncthreads();
    }
}

// ---------------- K4: hypergraph conv (unchanged) ----------------
__global__ __launch_bounds__(256)
void k_hyper(const float* __restrict__ h_all, const float* __restrict__ obs,
             const float* __restrict__ W_inc, const float* __restrict__ b_inc,
             const float* __restrict__ W_hg,
             float* __restrict__ graphs, uint32_t* __restrict__ emb_pk)
{
    __shared__ float hs[256];
    __shared__ float hm[128];
    __shared__ float rdv[16];
    __shared__ float rde[8];
    __shared__ float xs[16][64];
    __shared__ float msg[8][64];
    __shared__ float outs[16][64];
    int r = blockIdx.x;
    int t = threadIdx.x;
    hs[t] = h_all[(size_t)r*256 + t];
    __syncthreads();
    if (t < 128) {
        float a = b_inc[t];
#pragma unroll 8
        for (int k = 0; k < 256; ++k) a = fmaf(hs[k], W_inc[k*128 + t], a);
        float s = sigm(a);
        hm[t] = s;
        graphs[(size_t)r*128 + t] = s;
    }
    __syncthreads();
    if (t < 16) {
        float s = EPSV;
#pragma unroll
        for (int e = 0; e < 8; ++e) s += hm[t*8 + e];
        rdv[t] = 1.f/sqrtf(s);
    } else if (t >= 64 && t < 72) {
        int e = t - 64;
        float s = EPSV;
#pragma unroll
        for (int a2 = 0; a2 < 16; ++a2) s += hm[a2*8 + e];
        rde[e] = 1.f/s;
    }
    __syncthreads();
    {
        int aa = t >> 4, f4 = t & 15;
        float4 v = *(const float4*)(obs + (size_t)r*2048 + aa*128 + f4*4);
        float sc = rdv[aa];
        *(float4*)&xs[aa][f4*4] = make_float4(v.x*sc, v.y*sc, v.z*sc, v.w*sc);
    }
    __syncthreads();
#pragma unroll
    for (int rep = 0; rep < 2; ++rep) {
        int o = rep*256 + t;
        int e = o >> 6, f = o & 63;
        float s = 0.f;
#pragma unroll
        for (int a2 = 0; a2 < 16; ++a2) s = fmaf(hm[a2*8 + e], xs[a2][f], s);
        msg[e][f] = s * rde[e];
    }
    __syncthreads();
#pragma unroll
    for (int rep = 0; rep < 4; ++rep) {
        int o = rep*256 + t;
        int a2 = o >> 6, f = o & 63;
        float s = 0.f;
#pragma unroll
        for (int e = 0; e < 8; ++e) s = fmaf(hm[a2*8 + e], msg[e][f], s);
        outs[a2][f] = s * rdv[a2];
    }
    __syncthreads();
    {
        int aa = t >> 4, fo0 = (t & 15)*4;
        float s0=0,s1=0,s2=0,s3=0;
#pragma unroll 8
        for (int f = 0; f < 64; ++f) {
            float ov = outs[aa][f];
            float4 wv = *(const float4*)(W_hg + f*64 + fo0);
            s0 = fmaf(ov, wv.x, s0); s1 = fmaf(ov, wv.y, s1);
            s2 = fmaf(ov, wv.z, s2); s3 = fmaf(ov, wv.w, s3);
        }
        s0 = fmaxf(s0,0.f); s1 = fmaxf(s1,0.f); s2 = fmaxf(s2,0.f); s3 = fmaxf(s3,0.f);
        uint2 pk; pk.x = packh2(s0, s1); pk.y = packh2(s2, s3);
        *(uint2*)&emb_pk[((size_t)r*16 + aa)*32 + (t & 15)*2] = pk;
    }
}

// ---------------- K5: fused MLP head, MFMA; 128 rows/block, 8 waves ----------------
__global__ __launch_bounds__(512, 2)
void k_mlp(const uint32_t* __restrict__ emb_pk, const float* __restrict__ S1,
           const float* __restrict__ W1, const uint32_t* __restrict__ W1eT16,
           const uint32_t* __restrict__ W2T16,
           const float* __restrict__ b2, const float* __restrict__ W3,
           const float* __restrict__ b3, float* __restrict__ qout)
{
    __shared__ __align__(16) uint32_t x1s[16384];     // x1 [128][256] f16, chunk-swizzled
    __shared__ __align__(16) uint32_t wbuf[2][8192];  // 32KB each
    __shared__ float qpart[128][2];
    int tid = threadIdx.x;
    int lane = tid & 63, wave = tid >> 6;
    int wr = wave >> 1, wc = wave & 1;     // 4x1 row groups x 2 col groups
    int rowbase = blockIdx.x * 128;

    // stage W1eT [256][64] -> wbuf0 (2048 chunks), emb [128][64] -> wbuf1 (1024 chunks)
#pragma unroll
    for (int i = 0; i < 4; ++i) {
        int c = i*512 + tid;
        int row = c >> 3, kq = c & 7;
        gl_lds16(W1eT16 + (size_t)row*32 + ((kq ^ (row&7))<<2),
                 &wbuf[0][(size_t)((i*512 + (wave<<6))<<2)], lane);
    }
#pragma unroll
    for (int i = 0; i < 2; ++i) {
        int c = i*512 + tid;
        int row = c >> 3, kq = c & 7;
        gl_lds16(emb_pk + (size_t)(rowbase+row)*32 + ((kq ^ (row&7))<<2),
                 &wbuf[1][(size_t)((i*512 + (wave<<6))<<2)], lane);
    }
    // acc init = S1 (state@W1[:256]+b1) + W1 agent-onehot row
    f32x4 acc[2][8];
#pragma unroll
    for (int im = 0; im < 2; ++im)
#pragma unroll
        for (int in = 0; in < 8; ++in) {
            int col = wc*128 + in*16 + (lane & 15);
#pragma unroll
            for (int r = 0; r < 4; ++r) {
                int rl = wr*32 + im*16 + (lane >> 4)*4 + r;
                int grow = rowbase + rl;
                acc[im][in][r] = S1[(size_t)(grow >> 4)*256 + col]
                               + W1[(size_t)(256 + (grow & 15))*256 + col];
            }
        }
    __syncthreads();
    // phase A: += emb @ W1e  (K=64)
#pragma unroll
    for (int kk = 0; kk < 2; ++kk) {
        f16x8 af[2], bf[8];
#pragma unroll
        for (int im = 0; im < 2; ++im) {
            int row = wr*32 + im*16 + (lane & 15);
            int ck = (kk*4 + (lane >> 4)) ^ (row & 7);
            af[im] = *(const f16x8*)(&wbuf[1][row*32 + ck*4]);
        }
#pragma unroll
        for (int in = 0; in < 8; ++in) {
            int n = wc*128 + in*16 + (lane & 15);
            int ck = (kk*4 + (lane >> 4)) ^ (n & 7);
            bf[in] = *(const f16x8*)(&wbuf[0][n*32 + ck*4]);
        }
#pragma unroll
        for (int im = 0; im < 2; ++im)
#pragma unroll
            for (int in = 0; in < 8; ++in)
                acc[im][in] = MFMA16(af[im], bf[in], acc[im][in]);
    }
    // x1 = relu(acc) -> x1s (f16, chunk-swizzled); then clear acc
#pragma unroll
    for (int im = 0; im < 2; ++im)
#pragma unroll
        for (int in = 0; in < 8; ++in) {
            int col = wc*128 + in*16 + (lane & 15);
            int chunk = col >> 3, pos = col & 7;
#pragma unroll
            for (int r = 0; r < 4; ++r) {
                int rl = wr*32 + im*16 + (lane >> 4)*4 + r;
                int swc = chunk ^ (rl & 7);
                *((_Float16*)x1s + rl*256 + swc*8 + pos) =
                    (_Float16)fmaxf(acc[im][in][r], 0.f);
                acc[im][in][r] = 0.f;
            }
        }
    __syncthreads();
    // phase B: x2acc = x1 @ W2 (K=256, 4 chunks of 64, dbuf)
    auto STAGE_W2 = [&](int buf, int kc) {
#pragma unroll
        for (int i = 0; i < 4; ++i) {
            int c = i*512 + tid;
            int row = c >> 3, kq = c & 7;
            gl_lds16(W2T16 + (size_t)row*128 + kc*32 + ((kq ^ (row&7))<<2),
                     &wbuf[buf][(size_t)((i*512 + (wave<<6))<<2)], lane);
        }
    };
    STAGE_W2(0, 0);
    __syncthreads();
    for (int kc = 0; kc < 4; ++kc) {
        int cur = kc & 1;
        if (kc + 1 < 4) STAGE_W2(cur ^ 1, kc + 1);
#pragma unroll
        for (int kk = 0; kk < 2; ++kk) {
            f16x8 af[2], bf[8];
#pragma unroll
            for (int im = 0; im < 2; ++im) {
                int row = wr*32 + im*16 + (lane & 15);
                int g = kc*8 + kk*4 + (lane >> 4);
                int ck = g ^ (row & 7);
                af[im] = *(const f16x8*)(&x1s[row*128 + ck*4]);
            }
#pragma unroll
            for (int in = 0; in < 8; ++in) {
                int n = wc*128 + in*16 + (lane & 15);
                int ck = (kk*4 + (lane >> 4)) ^ (n & 7);
                bf[in] = *(const f16x8*)(&wbuf[cur][n*32 + ck*4]);
            }
#pragma unroll
            for (int im = 0; im < 2; ++im)
#pragma unroll
                for (int in = 0; in < 8; ++in)
                    acc[im][in] = MFMA16(af[im], bf[in], acc[im][in]);
        }
        __syncthreads();
    }
    // q epilogue: relu(acc+b2) dot W3, reduce over cols
    float w3v[8], b2v[8];
#pragma unroll
    for (int in = 0; in < 8; ++in) {
        int col = wc*128 + in*16 + (lane & 15);
        w3v[in] = W3[col]; b2v[in] = b2[col];
    }
#pragma unroll
    for (int im = 0; im < 2; ++im)
#pragma unroll
        for (int r = 0; r < 4; ++r) {
            float qp = 0.f;
#pragma unroll
            for (int in = 0; in < 8; ++in)
                qp = fmaf(fmaxf(acc[im][in][r] + b2v[in], 0.f), w3v[in], qp);
            qp += __shfl_xor(qp, 1);
            qp += __shfl_xor(qp, 2);
            qp += __shfl_xor(qp, 4);
            qp += __shfl_xor(qp, 8);
            if ((lane & 15) == 0)
                qpart[wr*32 + im*16 + (lane >> 4)*4 + r][wc] = qp;
        }
    __syncthreads();
    if (tid < 128)
        qout[rowbase + tid] = qpart[tid][0] + qpart[tid][1] + b3[0];
}

extern "C" void kernel_launch(void* const* d_in, const int* in_sizes, int n_in,
                              void* d_out, int out_size, void* d_ws, size_t ws_size,
                              hipStream_t stream)
{
    const float* state = (const float*)d_in[0];
    const float* obs   = (const float*)d_in[1];
    const float* Wx    = (const float*)d_in[2];
    const float* Wh    = (const float*)d_in[3];
    const float* b_gru = (const float*)d_in[4];
    const float* W_inc = (const float*)d_in[5];
    const float* b_inc = (const float*)d_in[6];
    const float* W_hg  = (const float*)d_in[7];
    const float* W1    = (const float*)d_in[8];
    const float* b1    = (const float*)d_in[9];
    const float* W2    = (const float*)d_in[10];
    const float* b2    = (const float*)d_in[11];
    const float* W3    = (const float*)d_in[12];
    const float* b3    = (const float*)d_in[13];
    float* qout   = (float*)d_out;
    float* graphs = (float*)d_out + NAR;

    float* base = (float*)d_ws;
    float* XG        = base;                              // 3,145,728 f
    float* hall      = base + 3145728;                    // 1,048,576 f
    float* S1        = base + 4194304;                    // 1,048,576 f
    uint32_t* emb_pk = (uint32_t*)(base + 5242880);       // 2,097,152 u32
    uint32_t* WhP    = (uint32_t*)(base + 7340032);       //    98,304 u32
    uint32_t* obs16  = (uint32_t*)(base + 7438336);       // 2,097,152 u32
    uint32_t* st16   = (uint32_t*)(base + 9535488);       //   524,288 u32
    uint32_t* WxT16  = (uint32_t*)(base + 10059776);      //   393,216 u32
    uint32_t* W1T16  = (uint32_t*)(base + 10452992);      //    32,768 u32
    uint32_t* W1eT16 = (uint32_t*)(base + 10485760);      //     8,192 u32
    uint32_t* W2T16  = (uint32_t*)(base + 10493952);      //    32,768 u32

    hipLaunchKernelGGL(k_prep_wh, dim3(384), dim3(256), 0, stream, Wh, WhP);
    hipLaunchKernelGGL(k_cvt_obs, dim3(2048), dim3(256), 0, stream, obs, obs16);
    hipLaunchKernelGGL(k_cvt_state, dim3(512), dim3(256), 0, stream, state, st16);
    hipLaunchKernelGGL(k_tr, dim3(16, 12), dim3(256), 0, stream, Wx, WxT16, 768, 512);
    hipLaunchKernelGGL(k_tr, dim3(4, 4), dim3(256), 0, stream, W1, W1T16, 256, 128);
    hipLaunchKernelGGL(k_tr, dim3(1, 4), dim3(256), 0, stream, W1 + 272*256, W1eT16, 256, 32);
    hipLaunchKernelGGL(k_tr, dim3(4, 4), dim3(256), 0, stream, W2, W2T16, 256, 128);
    hipLaunchKernelGGL(k_xg, dim3(192), dim3(256), 0, stream,
                       obs16, WxT16, b_gru, XG, 768, 1024, 6);
    hipLaunchKernelGGL(k_xg, dim3(64), dim3(256), 0, stream,
                       st16, W1T16, b1, S1, 256, 256, 2);
    hipLaunchKernelGGL(k_scan, dim3(32), dim3(512), 0, stream, WhP, XG, hall);
    hipLaunchKernelGGL(k_hyper, dim3(4096), dim3(256), 0, stream,
                       hall, obs, W_inc, b_inc, W_hg, graphs, emb_pk);
    hipLaunchKernelGGL(k_mlp, dim3(512), dim3(512), 0, stream,
                       emb_pk, S1, W1, W1eT16, W2T16, b2, W3, b3, qout);
}